// Round 2
// baseline (839.489 us; speedup 1.0000x reference)
//
#include <hip/hip_runtime.h>
#include <hip/hip_bf16.h>

// Problem constants
#define DIMC   1024
#define HEADS  16
#define HDIM   64
#define NTOK   64
#define BTOT   512
#define TABL   15

typedef __attribute__((ext_vector_type(8))) short short8;
typedef __attribute__((ext_vector_type(4))) float f32x4;
typedef __attribute__((ext_vector_type(8))) unsigned short u16x8;

static __device__ __forceinline__ void gload_lds16(const void* g, void* l) {
    __builtin_amdgcn_global_load_lds((const __attribute__((address_space(1))) void*)g,
                                     (__attribute__((address_space(3))) void*)l, 16, 0, 0);
}

static __device__ __forceinline__ unsigned short f2bf(float f) {
    __hip_bfloat16 h = __float2bfloat16(f);
    return *(unsigned short*)&h;
}

// ---------------- fp32 -> bf16 convert ----------------
__global__ void cvt_kernel(const float* __restrict__ in, unsigned short* __restrict__ out, int n4) {
    int stride = gridDim.x * blockDim.x;
    for (int i = blockIdx.x * blockDim.x + threadIdx.x; i < n4; i += stride) {
        float4 v = ((const float4*)in)[i];
        ushort4 o;
        o.x = f2bf(v.x); o.y = f2bf(v.y); o.z = f2bf(v.z); o.w = f2bf(v.w);
        ((ushort4*)out)[i] = o;
    }
}

// ---------------- GEMM: C[m][f] = sum_k A[m][k]*B[f][k] + bias[f] ----------------
// LDS layout: plane-major. Plane p (p=0..3) holds the 16B k-slice [k0+p*8, k0+p*8+8)
// of all 128 rows: ushort idx = p*1024 + row*8. Fragment reads are then
// row-consecutive 16B (2 lanes/bank = conflict-free). global_load_lds dest is
// linear within each plane; per-lane global source supplies the k-slice.
template<int NMAT, int MODE>
__global__ __launch_bounds__(256, 2)
void gemm_bt(const unsigned short* __restrict__ A,
             const unsigned short* __restrict__ B,
             const float* __restrict__ bias,
             float* __restrict__ Cf, unsigned short* __restrict__ Cb)
{
    constexpr int K  = 1024;
    __shared__ unsigned short Al[4096];
    __shared__ unsigned short Bl[4096];

    const int nbn  = NMAT / 128;
    const int bm   = blockIdx.x / nbn;
    const int bn   = blockIdx.x % nbn;
    const int tid  = threadIdx.x;
    const int lane = tid & 63;
    const int w    = tid >> 6;
    const int wm   = w >> 1, wn = w & 1;
    const int l15  = lane & 15, lg = lane >> 4;

    f32x4 acc[4][4] = {};

    const unsigned short* gA = A + (size_t)(bm * 128) * K;
    const unsigned short* gB = B + (size_t)(bn * 128) * K;

    for (int kt = 0; kt < K / 32; ++kt) {
        const int k0 = kt * 32;
        #pragma unroll
        for (int s = 0; s < 2; ++s) {
            const int chunk = w * 2 + s;          // 0..7
            const int plane = chunk >> 1;         // 0..3
            const int r0    = (chunk & 1) * 64;   // 0 or 64
            gload_lds16(gA + (size_t)(r0 + lane) * K + k0 + plane * 8,
                        (char*)Al + plane * 2048 + r0 * 16);
            gload_lds16(gB + (size_t)(r0 + lane) * K + k0 + plane * 8,
                        (char*)Bl + plane * 2048 + r0 * 16);
        }
        __syncthreads();
        short8 af[4], bfr[4];
        #pragma unroll
        for (int mt = 0; mt < 4; ++mt)
            af[mt] = *(const short8*)&Al[lg * 1024 + (wm * 64 + mt * 16 + l15) * 8];
        #pragma unroll
        for (int nt = 0; nt < 4; ++nt)
            bfr[nt] = *(const short8*)&Bl[lg * 1024 + (wn * 64 + nt * 16 + l15) * 8];
        #pragma unroll
        for (int mt = 0; mt < 4; ++mt)
            #pragma unroll
            for (int nt = 0; nt < 4; ++nt)
                acc[mt][nt] = __builtin_amdgcn_mfma_f32_16x16x32_bf16(af[mt], bfr[nt], acc[mt][nt], 0, 0, 0);
        __syncthreads();
    }

    #pragma unroll
    for (int mt = 0; mt < 4; ++mt) {
        #pragma unroll
        for (int nt = 0; nt < 4; ++nt) {
            const int f = bn * 128 + wn * 64 + nt * 16 + l15;
            const float bv = bias[f];
            #pragma unroll
            for (int r = 0; r < 4; ++r) {
                const int m = bm * 128 + wm * 64 + mt * 16 + lg * 4 + r;
                float val = acc[mt][nt][r] + bv;
                if (MODE == 0) {
                    if (f < 1024) val *= 0.125f;   // q scale = HD^-0.5
                    Cb[(size_t)m * NMAT + f] = f2bf(val);
                } else {
                    Cf[(size_t)m * NMAT + f] = val;
                }
            }
        }
    }
}

// ---------------- attention v2: swapped QK^T, in-register softmax ----------------
// One block per (window, head); wave w owns q-rows w*16..w*16+15.
// S^T tiles via mfma(A=K_frag, B=Q_frag): lane holds S[i=w*16+l15][j=jt*16+lg*4+r].
// Softmax: in-lane over 16 + shfl_xor(16,32). P relayout to PV A-frag via 16 shfls.
// LDS: q/k row-major with slot swizzle slot^=(row&7); vT with slot^=((d&7)^(d>>3)).
__global__ __launch_bounds__(256, 2)
void attn_kernel(const unsigned short* __restrict__ qkv,
                 const float* __restrict__ theta_max,
                 const float* __restrict__ a_p, const float* __restrict__ b_p,
                 const float* __restrict__ a_r, const float* __restrict__ b_r,
                 unsigned short* __restrict__ o_ws)
{
    const int bh = blockIdx.x;
    const int b  = bh >> 4;
    const int h  = bh & 15;
    const int tid = threadIdx.x, lane = tid & 63, w = tid >> 6;
    const int l15 = lane & 15, lg = lane >> 4;

    __shared__ unsigned short ql[4096];
    __shared__ unsigned short kl[4096];
    __shared__ unsigned short vtl[4096];   // transposed: row d, col j (swizzled)
    __shared__ float phiTab[15], thetaTab[15];

    if (tid < 15) {
        int az = tid - 7;
        int azm = az < 0 ? az + 15 : az;
        float ang = (float)az * 0.09817477042468103f;   // 2*pi/64
        phiTab[tid] = a_p[azm * 16 + h] * cosf(ang) + b_p[azm * 16 + h] * sinf(ang);
    } else if (tid >= 32 && tid < 47) {
        int rr = tid - 39;                               // [-7,7]
        int rm = rr < 0 ? rr + 15 : rr;
        float rn = (float)rr * theta_max[b >> 6] * 0.015625f;   // /64
        thetaTab[tid - 32] = a_r[rm * 16 + h] * cosf(rn) + b_r[rm * 16 + h] * sinf(rn);
    }

    // stage q, k (swizzled rows), v (swizzled transpose)
    const unsigned short* qg = qkv + (size_t)b * 64 * 3072 + h * 64;
    const unsigned short* kg = qg + 1024;
    const unsigned short* vg = qg + 2048;
    #pragma unroll
    for (int rep = 0; rep < 2; ++rep) {
        int idx = tid + rep * 256;       // 0..511
        int row = idx >> 3, seg = idx & 7;
        int qslot = seg ^ (row & 7);
        *(float4*)&ql[row * 64 + qslot * 8] = *(const float4*)&qg[(size_t)row * 3072 + seg * 8];
        *(float4*)&kl[row * 64 + qslot * 8] = *(const float4*)&kg[(size_t)row * 3072 + seg * 8];
        u16x8 vv = *(const u16x8*)&vg[(size_t)row * 3072 + seg * 8];
        #pragma unroll
        for (int e = 0; e < 8; ++e) {
            int d = seg * 8 + e;
            vtl[d * 64 + (row ^ ((e ^ seg) << 3))] = vv[e];
        }
    }
    __syncthreads();

    // Q B-fragments (row w*16+l15)
    const int qrow = w * 16 + l15;
    short8 qf[2];
    #pragma unroll
    for (int kc = 0; kc < 2; ++kc)
        qf[kc] = *(const short8*)&ql[qrow * 64 + (((kc * 4 + lg) ^ (l15 & 7)) * 8)];

    // S^T = K * Q^T : sacc[jt] lane -> S[i=w*16+l15][j=jt*16+lg*4+r]
    f32x4 sacc[4] = {};
    #pragma unroll
    for (int jt = 0; jt < 4; ++jt) {
        const int krow = jt * 16 + l15;
        #pragma unroll
        for (int kc = 0; kc < 2; ++kc) {
            short8 kf = *(const short8*)&kl[krow * 64 + (((kc * 4 + lg) ^ (l15 & 7)) * 8)];
            sacc[jt] = __builtin_amdgcn_mfma_f32_16x16x32_bf16(kf, qf[kc], sacc[jt], 0, 0, 0);
        }
    }

    // bias add: az depends on r only, rr depends on jt only
    float s[16];
    const int i7 = l15 & 7;
    const int ihi = w * 2 + (l15 >> 3);
    float phiv[4];
    #pragma unroll
    for (int r = 0; r < 4; ++r)
        phiv[r] = phiTab[i7 - ((lg * 4 + r) & 7) + 7];
    #pragma unroll
    for (int jt = 0; jt < 4; ++jt) {
        float thv = thetaTab[ihi - jt * 2 - (lg >> 1) + 7];
        #pragma unroll
        for (int r = 0; r < 4; ++r)
            s[jt * 4 + r] = sacc[jt][r] + phiv[r] + thv;
    }

    // softmax over the 64 j-values of row i: 16 in-lane + across lg (lane bits 4,5)
    float mx = s[0];
    #pragma unroll
    for (int t = 1; t < 16; ++t) mx = fmaxf(mx, s[t]);
    mx = fmaxf(mx, __shfl_xor(mx, 16));
    mx = fmaxf(mx, __shfl_xor(mx, 32));
    float sum = 0.f;
    #pragma unroll
    for (int t = 0; t < 16; ++t) { s[t] = __expf(s[t] - mx); sum += s[t]; }
    sum += __shfl_xor(sum, 16);
    sum += __shfl_xor(sum, 32);
    const float inv = 1.0f / sum;

    // pack P to bf16 pairs: W[jt][p] = {P[i][jt*16+lg*4+2p], +1}
    unsigned int W[4][2];
    #pragma unroll
    for (int jt = 0; jt < 4; ++jt)
        #pragma unroll
        for (int p = 0; p < 2; ++p)
            W[jt][p] = (unsigned int)f2bf(s[jt * 4 + 2 * p] * inv)
                     | ((unsigned int)f2bf(s[jt * 4 + 2 * p + 1] * inv) << 16);

    // relayout to PV A-frag: aw[kc][t] = P[i][kc*32+lg*8+2t .. +2t+1]
    const int srcA = l15 + (((lg << 1) & 3) << 4);
    const int srcB = l15 + ((((lg << 1) + 1) & 3) << 4);
    const bool hi = (lg >> 1) != 0;
    union { unsigned int u[4]; short8 v; } ap[2];
    #pragma unroll
    for (int kc = 0; kc < 2; ++kc) {
        #pragma unroll
        for (int t = 0; t < 4; ++t) {
            int src = (t < 2) ? srcA : srcB;
            unsigned int x0 = __shfl(W[kc * 2][t & 1], src);
            unsigned int x1 = __shfl(W[kc * 2 + 1][t & 1], src);
            ap[kc].u[t] = hi ? x1 : x0;
        }
    }

    // O = P @ V : B-frag from vtl (swizzled)
    f32x4 oacc[4] = {};
    #pragma unroll
    for (int dt = 0; dt < 4; ++dt) {
        const int d = dt * 16 + l15;
        const int sx = (d & 7) ^ (d >> 3);
        #pragma unroll
        for (int kc = 0; kc < 2; ++kc) {
            short8 bv = *(const short8*)&vtl[d * 64 + (((kc * 4 + lg) ^ sx) * 8)];
            oacc[dt] = __builtin_amdgcn_mfma_f32_16x16x32_bf16(ap[kc].v, bv, oacc[dt], 0, 0, 0);
        }
    }
    #pragma unroll
    for (int dt = 0; dt < 4; ++dt)
        #pragma unroll
        for (int r = 0; r < 4; ++r) {
            int i = w * 16 + lg * 4 + r;
            int d = dt * 16 + l15;
            o_ws[(size_t)(b * 64 + i) * 1024 + h * 64 + d] = f2bf(oacc[dt][r]);
        }
}

// ---------------- host ----------------
extern "C" void kernel_launch(void* const* d_in, const int* in_sizes, int n_in,
                              void* d_out, int out_size, void* d_ws, size_t ws_size,
                              hipStream_t stream) {
    const float* x      = (const float*)d_in[0];
    const float* theta  = (const float*)d_in[1];
    const float* qkv_w  = (const float*)d_in[2];
    const float* qkv_b  = (const float*)d_in[3];
    const float* proj_w = (const float*)d_in[4];
    const float* proj_b = (const float*)d_in[5];
    const float* a_p    = (const float*)d_in[6];
    const float* b_p    = (const float*)d_in[7];
    const float* a_r    = (const float*)d_in[8];
    const float* b_r    = (const float*)d_in[9];
    float* out = (float*)d_out;

    char* ws = (char*)d_ws;
    unsigned short* xb    = (unsigned short*)(ws);                      // 32768*1024*2 = 67108864
    unsigned short* wqkv  = (unsigned short*)(ws + 67108864);           // 3072*1024*2  = 6291456
    unsigned short* wproj = (unsigned short*)(ws + 73400320);           // 1024*1024*2  = 2097152
    unsigned short* qkvb  = (unsigned short*)(ws + 75497472);           // 32768*3072*2 = 201326592
    unsigned short* ob    = (unsigned short*)(ws + 276824064);          // 32768*1024*2 = 67108864
    // total 343932928 bytes

    // converts
    cvt_kernel<<<2048, 256, 0, stream>>>(x,      xb,    33554432 / 4);
    cvt_kernel<<<1024, 256, 0, stream>>>(qkv_w,  wqkv,  3145728 / 4);
    cvt_kernel<<<512,  256, 0, stream>>>(proj_w, wproj, 1048576 / 4);

    // qkv GEMM: M=32768, N=3072
    gemm_bt<3072, 0><<<dim3(256 * 24), dim3(256), 0, stream>>>(xb, wqkv, qkv_b, nullptr, qkvb);

    // attention: one block per (window, head)
    attn_kernel<<<dim3(512 * 16), dim3(256), 0, stream>>>(qkvb, theta, a_p, b_p, a_r, b_r, ob);

    // proj GEMM: M=32768, N=1024 -> fp32 out
    gemm_bt<1024, 1><<<dim3(256 * 8), dim3(256), 0, stream>>>(ob, wproj, proj_b, out, nullptr);
}

// Round 3
// 648.094 us; speedup vs baseline: 1.2953x; 1.2953x over previous
//
#include <hip/hip_runtime.h>
#include <hip/hip_bf16.h>

typedef __attribute__((ext_vector_type(8))) short short8;
typedef __attribute__((ext_vector_type(4))) float f32x4;
typedef __attribute__((ext_vector_type(8))) unsigned short u16x8;

static __device__ __forceinline__ void gload_lds16(const void* g, void* l) {
    __builtin_amdgcn_global_load_lds((const __attribute__((address_space(1))) void*)g,
                                     (__attribute__((address_space(3))) void*)l, 16, 0, 0);
}

static __device__ __forceinline__ unsigned short f2bf(float f) {
    __hip_bfloat16 h = __float2bfloat16(f);
    return *(unsigned short*)&h;
}

// ---------------- fp32 -> bf16 convert ----------------
__global__ void cvt_kernel(const float* __restrict__ in, unsigned short* __restrict__ out, int n4) {
    int stride = gridDim.x * blockDim.x;
    for (int i = blockIdx.x * blockDim.x + threadIdx.x; i < n4; i += stride) {
        float4 v = ((const float4*)in)[i];
        ushort4 o;
        o.x = f2bf(v.x); o.y = f2bf(v.y); o.z = f2bf(v.z); o.w = f2bf(v.w);
        ((ushort4*)out)[i] = o;
    }
}

// ---------------- GEMM: C[m][f] = sum_k A[m][k]*B[f][k] + bias[f] ----------------
// Round-1 coalesced staging (4 lanes x 16B per row = 64B runs) restored.
// XOR swizzle, both sides (rule 21): logical slot s of row r lives at phys slot
// s ^ ((r>>1)&3). Source: slot = (lane&3)^((lane>>3)&3); read: lg^((l15>>1)&3).
// Quarter-wave bank check: 8 distinct 16B quads x 2 lanes = conflict-free.
template<int NMAT, int MODE>
__global__ __launch_bounds__(256, 2)
void gemm_bt(const unsigned short* __restrict__ A,
             const unsigned short* __restrict__ B,
             const float* __restrict__ bias,
             float* __restrict__ Cf, unsigned short* __restrict__ Cb)
{
    constexpr int K  = 1024;
    __shared__ unsigned short Al[128 * 32];
    __shared__ unsigned short Bl[128 * 32];

    const int nbn = NMAT / 128;
    const int nwg = 256 * nbn;              // M/128 * nbn
    // bijective XCD swizzle (nwg % 8 == 0): consecutive wg per XCD -> L2 panel reuse
    const int orig = blockIdx.x;
    const int wg   = (orig & 7) * (nwg >> 3) + (orig >> 3);
    const int bm   = wg / nbn;
    const int bn   = wg % nbn;

    const int tid  = threadIdx.x;
    const int lane = tid & 63;
    const int w    = tid >> 6;
    const int wm   = w >> 1, wn = w & 1;
    const int l15  = lane & 15, lg = lane >> 4;

    f32x4 acc[4][4] = {};

    const int rsub = lane >> 2;                                 // row within 16-row segment
    const int scol = ((lane & 3) ^ ((lane >> 3) & 3)) * 8;      // swizzled k-slice (shorts)
    const unsigned short* gA = A + (size_t)(bm * 128) * K;
    const unsigned short* gB = B + (size_t)(bn * 128) * K;

    for (int kt = 0; kt < K / 32; ++kt) {
        const int k0 = kt * 32;
        #pragma unroll
        for (int s = 0; s < 2; ++s) {
            int seg = w * 2 + s;
            int row = seg * 16 + rsub;
            gload_lds16(gA + (size_t)row * K + k0 + scol, (char*)Al + seg * 1024);
            gload_lds16(gB + (size_t)row * K + k0 + scol, (char*)Bl + seg * 1024);
        }
        __syncthreads();
        const int rsw = (l15 >> 1) & 3;
        short8 af[4], bfr[4];
        #pragma unroll
        for (int mt = 0; mt < 4; ++mt)
            af[mt] = *(const short8*)&Al[(wm * 64 + mt * 16 + l15) * 32 + ((lg ^ rsw) * 8)];
        #pragma unroll
        for (int nt = 0; nt < 4; ++nt)
            bfr[nt] = *(const short8*)&Bl[(wn * 64 + nt * 16 + l15) * 32 + ((lg ^ rsw) * 8)];
        __builtin_amdgcn_s_setprio(1);
        #pragma unroll
        for (int mt = 0; mt < 4; ++mt)
            #pragma unroll
            for (int nt = 0; nt < 4; ++nt)
                acc[mt][nt] = __builtin_amdgcn_mfma_f32_16x16x32_bf16(af[mt], bfr[nt], acc[mt][nt], 0, 0, 0);
        __builtin_amdgcn_s_setprio(0);
        __syncthreads();
    }

    #pragma unroll
    for (int mt = 0; mt < 4; ++mt) {
        #pragma unroll
        for (int nt = 0; nt < 4; ++nt) {
            const int f = bn * 128 + wn * 64 + nt * 16 + l15;
            const float bv = bias[f];
            #pragma unroll
            for (int r = 0; r < 4; ++r) {
                const int m = bm * 128 + wm * 64 + mt * 16 + lg * 4 + r;
                float val = acc[mt][nt][r] + bv;
                if (MODE == 0) {
                    if (f < 1024) val *= 0.125f;   // q scale = HD^-0.5
                    Cb[(size_t)m * NMAT + f] = f2bf(val);
                } else {
                    Cf[(size_t)m * NMAT + f] = val;
                }
            }
        }
    }
}

// ---------------- attention v3 ----------------
// One block per (window, head); wave w owns q-rows w*16..w*16+15.
// Q fragments straight from global (no ql tile). K row-swizzled in LDS, V
// transposed+swizzled in LDS. Swapped QK^T -> in-register softmax -> shfl
// relayout -> PV. Output bounced through kl (freed after QK^T) for float4 stores.
__global__ __launch_bounds__(256, 2)
void attn_kernel(const unsigned short* __restrict__ qkv,
                 const float* __restrict__ theta_max,
                 const float* __restrict__ a_p, const float* __restrict__ b_p,
                 const float* __restrict__ a_r, const float* __restrict__ b_r,
                 unsigned short* __restrict__ o_ws)
{
    const int bh = blockIdx.x;
    const int b  = bh >> 4;
    const int h  = bh & 15;
    const int tid = threadIdx.x, lane = tid & 63, w = tid >> 6;
    const int l15 = lane & 15, lg = lane >> 4;

    __shared__ unsigned short kl[4096];
    __shared__ unsigned short vtl[4096];   // transposed: row d, col j (swizzled)
    __shared__ float phiTab[15], thetaTab[15];

    if (tid < 15) {
        int az = tid - 7;
        int azm = az < 0 ? az + 15 : az;
        float ang = (float)az * 0.09817477042468103f;   // 2*pi/64
        phiTab[tid] = a_p[azm * 16 + h] * cosf(ang) + b_p[azm * 16 + h] * sinf(ang);
    } else if (tid >= 32 && tid < 47) {
        int rr = tid - 39;                               // [-7,7]
        int rm = rr < 0 ? rr + 15 : rr;
        float rn = (float)rr * theta_max[b >> 6] * 0.015625f;   // /64
        thetaTab[tid - 32] = a_r[rm * 16 + h] * cosf(rn) + b_r[rm * 16 + h] * sinf(rn);
    }

    const unsigned short* qg = qkv + (size_t)b * 64 * 3072 + h * 64;
    const unsigned short* kg = qg + 1024;
    const unsigned short* vg = qg + 2048;

    // stage k (swizzled rows), v (swizzled transpose)
    #pragma unroll
    for (int rep = 0; rep < 2; ++rep) {
        int idx = tid + rep * 256;       // 0..511
        int row = idx >> 3, seg = idx & 7;
        *(float4*)&kl[row * 64 + (seg ^ (row & 7)) * 8] = *(const float4*)&kg[(size_t)row * 3072 + seg * 8];
        u16x8 vv = *(const u16x8*)&vg[(size_t)row * 3072 + seg * 8];
        #pragma unroll
        for (int e = 0; e < 8; ++e) {
            int d = seg * 8 + e;
            vtl[d * 64 + (row ^ ((e ^ seg) << 3))] = vv[e];
        }
    }

    // Q B-fragments direct from global (row w*16+l15)
    const int qrow = w * 16 + l15;
    short8 qf[2];
    #pragma unroll
    for (int kc = 0; kc < 2; ++kc)
        qf[kc] = *(const short8*)&qg[(size_t)qrow * 3072 + kc * 32 + lg * 8];
    __syncthreads();

    // S^T = K * Q^T : sacc[jt] lane -> S[i=w*16+l15][j=jt*16+lg*4+r]
    f32x4 sacc[4] = {};
    __builtin_amdgcn_s_setprio(1);
    #pragma unroll
    for (int jt = 0; jt < 4; ++jt) {
        const int krow = jt * 16 + l15;
        #pragma unroll
        for (int kc = 0; kc < 2; ++kc) {
            short8 kf = *(const short8*)&kl[krow * 64 + (((kc * 4 + lg) ^ (l15 & 7)) * 8)];
            sacc[jt] = __builtin_amdgcn_mfma_f32_16x16x32_bf16(kf, qf[kc], sacc[jt], 0, 0, 0);
        }
    }
    __builtin_amdgcn_s_setprio(0);

    // bias add: az depends on r only, rr depends on jt only
    float s[16];
    const int i7 = l15 & 7;
    const int ihi = w * 2 + (l15 >> 3);
    float phiv[4];
    #pragma unroll
    for (int r = 0; r < 4; ++r)
        phiv[r] = phiTab[i7 - ((lg * 4 + r) & 7) + 7];
    #pragma unroll
    for (int jt = 0; jt < 4; ++jt) {
        float thv = thetaTab[ihi - jt * 2 - (lg >> 1) + 7];
        #pragma unroll
        for (int r = 0; r < 4; ++r)
            s[jt * 4 + r] = sacc[jt][r] + phiv[r] + thv;
    }

    // softmax over 64 j per row i: 16 in-lane + shfl over lane bits 4,5
    float mx = s[0];
    #pragma unroll
    for (int t = 1; t < 16; ++t) mx = fmaxf(mx, s[t]);
    mx = fmaxf(mx, __shfl_xor(mx, 16));
    mx = fmaxf(mx, __shfl_xor(mx, 32));
    float sum = 0.f;
    #pragma unroll
    for (int t = 0; t < 16; ++t) { s[t] = __expf(s[t] - mx); sum += s[t]; }
    sum += __shfl_xor(sum, 16);
    sum += __shfl_xor(sum, 32);
    const float inv = 1.0f / sum;

    // pack P to bf16 pairs: W[jt][p] = {P[i][jt*16+lg*4+2p], next}
    unsigned int W[4][2];
    #pragma unroll
    for (int jt = 0; jt < 4; ++jt)
        #pragma unroll
        for (int p = 0; p < 2; ++p)
            W[jt][p] = (unsigned int)f2bf(s[jt * 4 + 2 * p] * inv)
                     | ((unsigned int)f2bf(s[jt * 4 + 2 * p + 1] * inv) << 16);

    // relayout to PV A-frag: ap[kc] = P[i][kc*32+lg*8 .. +7]
    const int srcA = l15 + (((lg << 1) & 3) << 4);
    const int srcB = l15 + ((((lg << 1) + 1) & 3) << 4);
    const bool hi = (lg >> 1) != 0;
    union { unsigned int u[4]; short8 v; } ap[2];
    #pragma unroll
    for (int kc = 0; kc < 2; ++kc) {
        #pragma unroll
        for (int t = 0; t < 4; ++t) {
            int src = (t < 2) ? srcA : srcB;
            unsigned int x0 = __shfl(W[kc * 2][t & 1], src);
            unsigned int x1 = __shfl(W[kc * 2 + 1][t & 1], src);
            ap[kc].u[t] = hi ? x1 : x0;
        }
    }

    // O = P @ V : B-frag from vtl (swizzled)
    f32x4 oacc[4] = {};
    __builtin_amdgcn_s_setprio(1);
    #pragma unroll
    for (int dt = 0; dt < 4; ++dt) {
        const int d = dt * 16 + l15;
        const int sx = (d & 7) ^ (d >> 3);
        #pragma unroll
        for (int kc = 0; kc < 2; ++kc) {
            short8 bv = *(const short8*)&vtl[d * 64 + (((kc * 4 + lg) ^ sx) * 8)];
            oacc[dt] = __builtin_amdgcn_mfma_f32_16x16x32_bf16(ap[kc].v, bv, oacc[dt], 0, 0, 0);
        }
    }
    __builtin_amdgcn_s_setprio(0);

    // bounce O through kl (freed: kf reads done by all waves after this barrier)
    __syncthreads();
    #pragma unroll
    for (int dt = 0; dt < 4; ++dt)
        #pragma unroll
        for (int r = 0; r < 4; ++r) {
            int i = w * 16 + lg * 4 + r;
            int d = dt * 16 + l15;
            kl[i * 64 + d] = f2bf(oacc[dt][r]);
        }
    __syncthreads();
    // vectorized global store: 8 lanes x 16B = 128B per row
    #pragma unroll
    for (int rep = 0; rep < 2; ++rep) {
        int idx = tid + rep * 256;
        int row = idx >> 3, seg = idx & 7;
        *(float4*)&o_ws[(size_t)(b * 64 + row) * 1024 + h * 64 + seg * 8] =
            *(const float4*)&kl[row * 64 + seg * 8];
    }
}

// ---------------- host ----------------
extern "C" void kernel_launch(void* const* d_in, const int* in_sizes, int n_in,
                              void* d_out, int out_size, void* d_ws, size_t ws_size,
                              hipStream_t stream) {
    const float* x      = (const float*)d_in[0];
    const float* theta  = (const float*)d_in[1];
    const float* qkv_w  = (const float*)d_in[2];
    const float* qkv_b  = (const float*)d_in[3];
    const float* proj_w = (const float*)d_in[4];
    const float* proj_b = (const float*)d_in[5];
    const float* a_p    = (const float*)d_in[6];
    const float* b_p    = (const float*)d_in[7];
    const float* a_r    = (const float*)d_in[8];
    const float* b_r    = (const float*)d_in[9];
    float* out = (float*)d_out;

    char* ws = (char*)d_ws;
    unsigned short* xb    = (unsigned short*)(ws);                      // 32768*1024*2 = 67108864
    unsigned short* wqkv  = (unsigned short*)(ws + 67108864);           // 3072*1024*2  = 6291456
    unsigned short* wproj = (unsigned short*)(ws + 73400320);           // 1024*1024*2  = 2097152
    unsigned short* qkvb  = (unsigned short*)(ws + 75497472);           // 32768*3072*2 = 201326592
    unsigned short* ob    = (unsigned short*)(ws + 276824064);          // 32768*1024*2 = 67108864
    // total 343932928 bytes

    cvt_kernel<<<2048, 256, 0, stream>>>(x,      xb,    33554432 / 4);
    cvt_kernel<<<1024, 256, 0, stream>>>(qkv_w,  wqkv,  3145728 / 4);
    cvt_kernel<<<512,  256, 0, stream>>>(proj_w, wproj, 1048576 / 4);

    // qkv GEMM: M=32768, N=3072
    gemm_bt<3072, 0><<<dim3(256 * 24), dim3(256), 0, stream>>>(xb, wqkv, qkv_b, nullptr, qkvb);

    // attention: one block per (window, head)
    attn_kernel<<<dim3(512 * 16), dim3(256), 0, stream>>>(qkvb, theta, a_p, b_p, a_r, b_r, ob);

    // proj GEMM: M=32768, N=1024 -> fp32 out
    gemm_bt<1024, 1><<<dim3(256 * 8), dim3(256), 0, stream>>>(ob, wproj, proj_b, out, nullptr);
}